// Round 5
// baseline (105.370 us; speedup 1.0000x reference)
//
#include <hip/hip_runtime.h>

// Non-backtracking random walk, 32 steps.
// out = [walks (steps+1,n) ; walk_edges (steps,n)] int32.
//
// R13: dual parallel gathers. R11+R12 refuted request-count as the binder
// (2->1 req/step bought only ~3 us). New theory: the predicated alt-load
// serializes the wave — P(any of 128 lane-chains backtracks) ~ 99.97%, so
// EVERY wave-step ran a second memory op dependent on the first gather's
// result, plus exec-mask/branch overhead. The alt ADDRESS never depended
// on the first load (only the selection does), so issue chosen+alt
// dwordx2 together (4 independent loads in flight per step with 2 chains)
// and select afterwards. Also: validate kernel deleted — its register
// decode-check is folded into pack (the dwordx2@4B-align HW question it
// guarded was settled by R12's passing fast path). Format unchanged:
// 18-bit entries, 36B/row, 3.6MB L2-resident, one alignbit decode.

#define DEG 16
#define CHAINS 2
#define NMAX 131072          // row-count limit of the packed table
#define PACK_BLOCK 256
#define ENT_MASK 0x3FFFFu    // 18-bit entries

// Packed adjacency: 9 dwords/row = 16 x 18-bit entries, +2 dwords pad so
// the last row's entry-15 dwordx2 (dwords 8,9) stays in-bounds.
__device__ unsigned int g_pk32[(size_t)NMAX * 9 + 2];
__device__ int g_flag;   // == epoch  =>  take the general fallback

__global__ __launch_bounds__(PACK_BLOCK) void pack_check_kernel(
    const int* __restrict__ adj_nodes,
    const int* __restrict__ adj_offset,
    const int* __restrict__ degrees,
    int n, int epoch) {
    __shared__ __align__(16) unsigned int lds[PACK_BLOCK * 9];

    int tid = threadIdx.x;
    int blockStart = blockIdx.x * PACK_BLOCK;
    int v = blockStart + tid;

    bool bad = false;
    if (v < n) {
        bad = (degrees[v] != DEG) || (adj_offset[v] != v * DEG);

        const uint4* row4 = (const uint4*)(adj_nodes + (size_t)v * DEG); // 64B-aligned
        uint4 r[4];
        r[0] = row4[0]; r[1] = row4[1]; r[2] = row4[2]; r[3] = row4[3];
        const unsigned* rr = (const unsigned*)r;

        unsigned dw[9];
#pragma unroll
        for (int j = 0; j < 9; ++j) dw[j] = 0u;
#pragma unroll
        for (int e = 0; e < 16; ++e) {
            unsigned id = rr[e];
            if (id >= 262144u) bad = true;            // needs >18 bits
            unsigned s   = 18u * (unsigned)e;
            unsigned d   = s >> 5;
            unsigned off = s & 31u;
            dw[d] |= id << off;
            if (off > 14u) dw[d + 1] |= id >> (32u - off);  // field crosses dword
        }
        // register-level decode check through the walker's exact alignbit
        // path (guards pack logic; costs ~100 VALU ops, no memory)
#pragma unroll
        for (int e = 0; e < 16; ++e) {
            unsigned s   = 18u * (unsigned)e;
            unsigned d   = s >> 5;
            unsigned off = s & 31u;
            unsigned hi  = (off > 14u) ? dw[d + 1] : 0u;   // crossing d's are <=7
            unsigned id  = __builtin_amdgcn_alignbit(hi, dw[d], off) & ENT_MASK;
            if (id != rr[e]) bad = true;
        }
#pragma unroll
        for (int j = 0; j < 9; ++j) lds[tid * 9 + j] = dw[j];
    }
    __syncthreads();

    // coalesced flush: 256 rows * 9 dwords = 2304 dwords = 576 uint4
    int rows = n - blockStart;
    if (rows > PACK_BLOCK) rows = PACK_BLOCK;
    unsigned int* dstBase = g_pk32 + (size_t)blockStart * 9;   // 16B-aligned (9216B/block)
    if (rows == PACK_BLOCK) {
        uint4* dst4 = (uint4*)dstBase;
        const uint4* src4 = (const uint4*)lds;
        for (int i = tid; i < (PACK_BLOCK * 9) / 4; i += PACK_BLOCK)
            dst4[i] = src4[i];
    } else {
        int ndw = rows * 9;
        for (int i = tid; i < ndw; i += PACK_BLOCK) dstBase[i] = lds[i];
    }

    if (bad) g_flag = epoch;
}

template <int STEPS>
__global__ __launch_bounds__(64) void walker_fast5(
    const int* __restrict__ choices,
    int* __restrict__ out, int n, int h, int epoch,
    const int* __restrict__ adj_nodes,
    const int* __restrict__ adj_offset,
    const int* __restrict__ degrees) {

    int t = blockIdx.x * blockDim.x + threadIdx.x;
    if (t >= h) return;

    int* walks      = out;                    // [STEPS+1, n]
    int* walk_edges = out + (STEPS + 1) * n;  // [STEPS, n]

    int w0 = t;
    int w1 = t + h;
    bool has1 = (w1 < n);
    int w1s = has1 ? w1 : w0;

    __builtin_nontemporal_store(w0, &walks[w0]);
    if (has1) __builtin_nontemporal_store(w1, &walks[w1]);

    if (g_flag != epoch) {
        // ---- fast path: uniform CSR deg=16, dual parallel gathers ----
        int c0[STEPS], c1[STEPS];
#pragma unroll
        for (int i = 0; i < STEPS; ++i) {
            c0[i] = __builtin_nontemporal_load(&choices[i * n + w0]);
            c1[i] = __builtin_nontemporal_load(&choices[i * n + w1s]);
        }

        int prev0 = -1, cur0 = w0;
        int prev1 = -1, cur1 = w1s;
#pragma unroll
        for (int i = 0; i < STEPS; ++i) {
            unsigned ch0 = (unsigned)c0[i];
            unsigned ch1 = (unsigned)c1[i];
            unsigned e0 = ch0 & (DEG - 1);
            unsigned e1 = ch1 & (DEG - 1);
            // alt index is load-independent: compute upfront
            unsigned a0 = (e0 + 1u + ch0 % (DEG - 1)) & (DEG - 1);
            unsigned a1 = (e1 + 1u + ch1 % (DEG - 1)) & (DEG - 1);

            const unsigned* row0 = g_pk32 + (size_t)(unsigned)cur0 * 9u;
            const unsigned* row1 = g_pk32 + (size_t)(unsigned)cur1 * 9u;

            unsigned s0 = 18u * e0, d0 = s0 >> 5, f0 = s0 & 31u;
            unsigned s1 = 18u * e1, d1 = s1 >> 5, f1 = s1 & 31u;
            unsigned sa = 18u * a0, da = sa >> 5, fa = sa & 31u;
            unsigned sb = 18u * a1, db = sb >> 5, fb = sb & 31u;

            // four INDEPENDENT gathers, all in flight together; alt shares
            // the chosen entry's row (same/adjacent 64B line -> MSHR merge)
            uint2 q0 = *(const uint2*)(row0 + d0);
            uint2 qa = *(const uint2*)(row0 + da);
            uint2 q1 = *(const uint2*)(row1 + d1);
            uint2 qb = *(const uint2*)(row1 + db);

            int n00 = (int)(__builtin_amdgcn_alignbit(q0.y, q0.x, f0) & ENT_MASK);
            int n0a = (int)(__builtin_amdgcn_alignbit(qa.y, qa.x, fa) & ENT_MASK);
            int n10 = (int)(__builtin_amdgcn_alignbit(q1.y, q1.x, f1) & ENT_MASK);
            int n1b = (int)(__builtin_amdgcn_alignbit(qb.y, qb.x, fb) & ENT_MASK);

            // branchless select (no exec-mask churn, no dependent load)
            bool bt0 = (n00 == prev0);
            bool bt1 = (n10 == prev1);
            int nw0 = bt0 ? n0a : n00;
            int nw1 = bt1 ? n1b : n10;
            unsigned ef0 = bt0 ? a0 : e0;
            unsigned ef1 = bt1 ? a1 : e1;

            int ce0 = (cur0 << 4) + (int)ef0;
            int ce1 = (cur1 << 4) + (int)ef1;

            __builtin_nontemporal_store(nw0, &walks[(i + 1) * n + w0]);
            __builtin_nontemporal_store(ce0, &walk_edges[i * n + w0]);
            if (has1) {
                __builtin_nontemporal_store(nw1, &walks[(i + 1) * n + w1]);
                __builtin_nontemporal_store(ce1, &walk_edges[i * n + w1]);
            }
            prev0 = cur0; cur0 = nw0;
            prev1 = cur1; cur1 = nw1;
        }
    } else {
        // ---- general fallback: 2 dependent gathers/step ----
        for (int k = 0; k < 2; ++k) {
            int w = (k == 0) ? w0 : w1;
            if (w >= n) break;
            int prev = -1, cur = w;
            for (int i = 0; i < STEPS; ++i) {
                int chv = choices[i * n + w];
                int deg = degrees[cur];
                int off = adj_offset[cur];
                int nb  = deg - 1 > 1 ? deg - 1 : 1;

                int e      = chv % deg;
                int chosen = off + e;
                int alt    = off + (e + 1 + chv % nb) % deg;

                int nv0 = adj_nodes[chosen];
                int nv1 = adj_nodes[alt];

                bool bt = (nv0 == prev);
                int nw  = bt ? nv1 : nv0;
                walks[(i + 1) * n + w] = nw;
                walk_edges[i * n + w]  = bt ? alt : chosen;
                prev = cur;
                cur  = nw;
            }
        }
    }
}

__global__ __launch_bounds__(256) void walker_generic(
    const int* __restrict__ adj_nodes,
    const int* __restrict__ adj_offset,
    const int* __restrict__ degrees,
    const int* __restrict__ choices,
    int* __restrict__ out, int n, int steps) {

    int w = blockIdx.x * blockDim.x + threadIdx.x;
    if (w >= n) return;

    int* walks      = out;
    int* walk_edges = out + (steps + 1) * n;
    walks[w] = w;

    int prev = -1, cur = w;
    for (int i = 0; i < steps; ++i) {
        int chv = choices[i * n + w];
        int deg = degrees[cur];
        int off = adj_offset[cur];
        int nb  = deg - 1 > 1 ? deg - 1 : 1;

        int e      = chv % deg;
        int chosen = off + e;
        int alt    = off + (e + 1 + chv % nb) % deg;

        int nv0 = adj_nodes[chosen];
        int nv1 = adj_nodes[alt];

        bool bt = (nv0 == prev);
        int nw  = bt ? nv1 : nv0;
        walks[(i + 1) * n + w] = nw;
        walk_edges[i * n + w]  = bt ? alt : chosen;
        prev = cur;
        cur  = nw;
    }
}

extern "C" void kernel_launch(void* const* d_in, const int* in_sizes, int n_in,
                              void* d_out, int out_size, void* d_ws, size_t ws_size,
                              hipStream_t stream) {
    // inputs: 0=x (unused), 1=adj_nodes, 2=adj_offset, 3=degrees, 4=choices
    const int* adj_nodes  = (const int*)d_in[1];
    const int* adj_offset = (const int*)d_in[2];
    const int* degrees    = (const int*)d_in[3];
    const int* choices    = (const int*)d_in[4];
    int* out = (int*)d_out;

    int n     = in_sizes[2];
    int steps = in_sizes[4] / n;

    if (steps == 32 && n <= NMAX) {
        static int s_epoch = 0;
        int epoch = ++s_epoch;   // baked into a captured graph; pack reruns
                                 // per replay, badness is input-constant

        int pg = (n + PACK_BLOCK - 1) / PACK_BLOCK;
        pack_check_kernel<<<pg, PACK_BLOCK, 0, stream>>>(adj_nodes, adj_offset,
                                                         degrees, n, epoch);

        int h  = (n + CHAINS - 1) / CHAINS;
        int wb = 64, wg = (h + wb - 1) / wb;
        walker_fast5<32><<<wg, wb, 0, stream>>>(choices, out, n, h, epoch,
                                                adj_nodes, adj_offset, degrees);
    } else {
        int block = 256, grid = (n + block - 1) / block;
        walker_generic<<<grid, block, 0, stream>>>(adj_nodes, adj_offset,
                                                   degrees, choices, out, n, steps);
    }
}